// Round 10
// baseline (444.888 us; speedup 1.0000x reference)
//
#include <hip/hip_runtime.h>

#define TOK 4096
#define HD 1024
#define ID 4096
#define NE 8

typedef __attribute__((ext_vector_type(4))) float f32x4;
typedef __attribute__((ext_vector_type(8))) __bf16 bf16x8;
typedef __attribute__((ext_vector_type(8))) unsigned short u16x8;

// LDS rows are 64B (BK=32 bf16) = 4 x 16B slots; swizzle slot s -> s ^ ((row>>1)&3).
#define SSW(r, s) ((((s) ^ (((r) >> 1) & 3))) << 4)

// compiler emits v_cvt_pk_bf16_f32 (RNE) for scalar casts -- do NOT hand-roll (m240)
__device__ __forceinline__ bf16x8 pack8(f32x4 a, f32x4 b) {
  bf16x8 r;
#pragma unroll
  for (int i = 0; i < 4; ++i) { r[i] = (__bf16)a[i]; r[i + 4] = (__bf16)b[i]; }
  return r;
}

__device__ __forceinline__ float gelu_tanh(float g) {
  float z = 0.7978845608028654f * (g + 0.044715f * g * g * g);
  float t = __expf(-2.0f * z);
  return g / (1.0f + t);
}

// barrier that does NOT drain vmcnt: LDS ordering via lgkmcnt(0), global prefetch stays in flight
__device__ __forceinline__ void bar_lgkm() {
  asm volatile("s_waitcnt lgkmcnt(0)" ::: "memory");
  __builtin_amdgcn_s_barrier();
}

__global__ void init_k(int* __restrict__ meta) {
  if (threadIdx.x < 16) meta[threadIdx.x] = 0;
}

// one wave per token: fp32 logits (argmax must match numpy fp32), top1 via first-max
__global__ void router_k(const float* __restrict__ x, const float* __restrict__ gw,
                         float* __restrict__ logits, int* __restrict__ top1) {
  const int wid = threadIdx.x >> 6;
  const int lane = threadIdx.x & 63;
  const int t = blockIdx.x * 4 + wid;
  const float* xr = x + (size_t)t * HD;
  float acc[NE];
#pragma unroll
  for (int e = 0; e < NE; ++e) acc[e] = 0.0f;
#pragma unroll
  for (int c = 0; c < 4; ++c) {
    const int k = (c * 64 + lane) * 4;
    f32x4 xv = *(const f32x4*)(xr + k);
#pragma unroll
    for (int e = 0; e < NE; ++e) {
      f32x4 gv = *(const f32x4*)(gw + e * HD + k);
      acc[e] += xv[0] * gv[0] + xv[1] * gv[1] + xv[2] * gv[2] + xv[3] * gv[3];
    }
  }
#pragma unroll
  for (int off = 32; off > 0; off >>= 1) {
#pragma unroll
    for (int e = 0; e < NE; ++e) acc[e] += __shfl_xor(acc[e], off, 64);
  }
  if (lane == 0) {
    int best = 0; float bv = acc[0];
#pragma unroll
    for (int e = 1; e < NE; ++e) if (acc[e] > bv) { bv = acc[e]; best = e; }
    top1[t] = best;
#pragma unroll
    for (int e = 0; e < NE; ++e) logits[(size_t)t * NE + e] = acc[e];
  }
}

__global__ void hist_k(const int* __restrict__ top1, int* __restrict__ counts) {
  int t = blockIdx.x * 256 + threadIdx.x;
  atomicAdd(&counts[top1[t]], 1);
}

__global__ void offsets_k(const int* __restrict__ counts, int* __restrict__ offsets) {
  if (threadIdx.x == 0) {
    int s = 0;
    for (int e = 0; e < NE; ++e) { offsets[e] = s; s += counts[e]; }
  }
}

__global__ void scatter_k(const int* __restrict__ top1, const int* __restrict__ offsets,
                          int* __restrict__ counts2, int* __restrict__ perm) {
  int t = blockIdx.x * 256 + threadIdx.x;
  int e = top1[t];
  int slot = atomicAdd(&counts2[e], 1);
  perm[offsets[e] + slot] = t;
}

// compact permuted bf16 copy of x: xp[p,:] = bf16(x[perm[p],:])
__global__ void xp_k(const float* __restrict__ x, const int* __restrict__ perm,
                     unsigned short* __restrict__ xp) {
  const int p = blockIdx.x * 4 + (threadIdx.x >> 6);
  const int lane = threadIdx.x & 63;
  const float* src = x + (size_t)perm[p] * HD + lane * 16;
  unsigned short* dst = xp + (size_t)p * HD + lane * 16;
  f32x4 v0 = *(const f32x4*)(src);
  f32x4 v1 = *(const f32x4*)(src + 4);
  f32x4 v2 = *(const f32x4*)(src + 8);
  f32x4 v3 = *(const f32x4*)(src + 12);
  *(bf16x8*)(dst) = pack8(v0, v1);
  *(bf16x8*)(dst + 8) = pack8(v2, v3);
}

// gemm1: BM=128 tok x 128 out-cols, B-LDS = 256 rows (128 gate + 128 up), BK=32.
// 512 thr / 8 waves = 2wm x {wn0,1=gate | wn2,3=up}, wave 64x64, acc 4x4.
// dbuf LDS + depth-4 reg prefetch (parity-unrolled), one lgkm-barrier per tile.
// bid map: (en>>3)*256 + mt*8 + (en&7) -> mt-siblings adjacent AND same XCD (bid%8=en&7):
// weight panel fetched from HBM once into one L2, siblings L2-hit.
__global__ __launch_bounds__(512, 2) void gemm1_k(
    const unsigned short* __restrict__ xp, const float* __restrict__ wg,
    const float* __restrict__ wu, const int* __restrict__ counts,
    const int* __restrict__ offsets, unsigned short* __restrict__ hidden) {
  const int bid = blockIdx.x;
  const int en = (bid >> 8) * 8 + (bid & 7);   // 0..255
  const int mt = (bid >> 3) & 31;
  const int e = en >> 5, nt = en & 31;
  const int ne = counts[e];
  if (mt * 128 >= ne) return;
  const int off = offsets[e];

  __shared__ __align__(16) char lds[67584];  // A 2x8K @0, B 2x16K @16384; epilogue ex 128x132 f32

  const int tid = threadIdx.x;
  const int lane = tid & 63;
  const int wid = tid >> 6;
  const int wm = wid >> 2;            // 0..1
  const int wn = wid & 3;             // 0,1 gate | 2,3 up
  const int wrow = wm * 64;
  const int frow = lane & 15;
  const int fk = lane >> 4;           // 0..3 slot
  const int brow0 = (wn < 2) ? wn * 64 : 128 + (wn - 2) * 64;

  // A staging: 4 thr/row, 16B each. row=tid>>2, slot=tid&3
  const int ar = tid >> 2, as = tid & 3;
  int tokrow = off + mt * 128 + ar;
  if (tokrow >= TOK) tokrow = TOK - 1;           // masked at store
  const unsigned short* asrc = xp + (size_t)tokrow * HD + as * 8;

  // B staging: 2 thr/row, 64B fp32 each. row=tid>>1 (0-127 gate,128-255 up), half=tid&1
  const int br = tid >> 1, bh = tid & 1;
  const float* bsrc = (br < 128)
      ? wg + ((size_t)e * ID + nt * 128 + br) * HD + bh * 16
      : wu + ((size_t)e * ID + nt * 128 + (br - 128)) * HD + bh * 16;
  const int bs0 = (2 * bh) ^ ((br >> 1) & 3);
  const int bs1 = (2 * bh + 1) ^ ((br >> 1) & 3);

  f32x4 acc[4][4] = {};
  u16x8 rAv[4];
  f32x4 rBv[4][4];

#define G1_LOAD(kt, p)                                                   \
  do {                                                                   \
    rAv[p] = *(const u16x8*)(asrc + (kt) * 32);                          \
    const float* b_ = bsrc + (kt) * 32;                                  \
    _Pragma("unroll") for (int i = 0; i < 4; ++i)                        \
      rBv[p][i] = *(const f32x4*)(b_ + i * 4);                           \
  } while (0)

#define G1_WRITE(p)                                                      \
  do {                                                                   \
    *(u16x8*)(lds + ((p) & 1) * 8192 + ar * 64 + SSW(ar, as)) = rAv[p];  \
    *(bf16x8*)(lds + 16384 + ((p) & 1) * 16384 + br * 64 + (bs0 << 4)) = pack8(rBv[p][0], rBv[p][1]); \
    *(bf16x8*)(lds + 16384 + ((p) & 1) * 16384 + br * 64 + (bs1 << 4)) = pack8(rBv[p][2], rBv[p][3]); \
  } while (0)

#define G1_COMPUTE(p)                                                    \
  do {                                                                   \
    bf16x8 af[4], bb[4];                                                 \
    _Pragma("unroll") for (int mi = 0; mi < 4; ++mi) {                   \
      const int r_ = wrow + mi * 16 + frow;                              \
      af[mi] = *(const bf16x8*)(lds + ((p) & 1) * 8192 + r_ * 64 + SSW(r_, fk)); \
    }                                                                    \
    _Pragma("unroll") for (int ni = 0; ni < 4; ++ni) {                   \
      const int r_ = brow0 + ni * 16 + frow;                             \
      bb[ni] = *(const bf16x8*)(lds + 16384 + ((p) & 1) * 16384 + r_ * 64 + SSW(r_, fk)); \
    }                                                                    \
    __builtin_amdgcn_s_setprio(1);                                       \
    _Pragma("unroll") for (int mi = 0; mi < 4; ++mi)                     \
      _Pragma("unroll") for (int ni = 0; ni < 4; ++ni)                   \
        acc[mi][ni] = __builtin_amdgcn_mfma_f32_16x16x32_bf16(af[mi], bb[ni], acc[mi][ni], 0, 0, 0); \
    __builtin_amdgcn_s_setprio(0);                                       \
  } while (0)

  const int NIT = HD / 32;  // 32
  G1_LOAD(0, 0); G1_LOAD(1, 1); G1_LOAD(2, 2); G1_LOAD(3, 3);
  for (int ks = 0; ks < NIT; ks += 4) {
    G1_WRITE(0); bar_lgkm(); if (ks + 4 < NIT) G1_LOAD(ks + 4, 0); G1_COMPUTE(0);
    G1_WRITE(1); bar_lgkm(); if (ks + 5 < NIT) G1_LOAD(ks + 5, 1); G1_COMPUTE(1);
    G1_WRITE(2); bar_lgkm(); if (ks + 6 < NIT) G1_LOAD(ks + 6, 2); G1_COMPUTE(2);
    G1_WRITE(3); bar_lgkm(); if (ks + 7 < NIT) G1_LOAD(ks + 7, 3); G1_COMPUTE(3);
  }
#undef G1_LOAD
#undef G1_WRITE
#undef G1_COMPUTE

  // epilogue: gate waves -> LDS exchange; up waves fuse gelu(g)*u -> hidden bf16
  __syncthreads();
  float* ex = (float*)lds;  // [128][132]
  if (wn < 2) {
#pragma unroll
    for (int mi = 0; mi < 4; ++mi)
#pragma unroll
      for (int ni = 0; ni < 4; ++ni)
#pragma unroll
        for (int j = 0; j < 4; ++j) {
          const int row = wrow + mi * 16 + fk * 4 + j;
          ex[row * 132 + wn * 64 + ni * 16 + frow] = acc[mi][ni][j];
        }
  }
  __syncthreads();
  if (wn >= 2) {
#pragma unroll
    for (int mi = 0; mi < 4; ++mi)
#pragma unroll
      for (int j = 0; j < 4; ++j) {
        const int row = wrow + mi * 16 + fk * 4 + j;
        const int grow = mt * 128 + row;
        if (grow < ne) {
          unsigned short* hrow = hidden + (size_t)(off + grow) * ID + nt * 128 + (wn - 2) * 64;
#pragma unroll
          for (int ni = 0; ni < 4; ++ni) {
            float g = ex[row * 132 + (wn - 2) * 64 + ni * 16 + frow];
            __bf16 hb = (__bf16)(gelu_tanh(g) * acc[mi][ni][j]);
            hrow[ni * 16 + frow] = __builtin_bit_cast(unsigned short, hb);
          }
        }
      }
  }
}

// gemm2: out[token] = hidden[p] @ wd[e]^T. BM=128 x BN=128, BK=32, 256 thr / 4 waves (2x2),
// wave 64x64 acc 4x4. Same dbuf + depth-4 prefetch + 1 barrier/tile + same bid map.
__global__ __launch_bounds__(256, 2) void gemm2_k(
    const unsigned short* __restrict__ hidden, const float* __restrict__ wd,
    const int* __restrict__ perm, const int* __restrict__ counts,
    const int* __restrict__ offsets, float* __restrict__ out) {
  const int bid = blockIdx.x;
  const int en = (bid >> 8) * 8 + (bid & 7);   // 0..63
  const int mt = (bid >> 3) & 31;
  const int e = en >> 3, nt = en & 7;
  const int ne = counts[e];
  if (mt * 128 >= ne) return;
  const int off = offsets[e];

  __shared__ __align__(16) char lds[32768];  // A 2x8K @0, B 2x8K @16384

  const int tid = threadIdx.x;
  const int lane = tid & 63;
  const int wid = tid >> 6;
  const int wm = wid >> 1, wn = wid & 1;
  const int wrow = wm * 64, wcol = wn * 64;
  const int frow = lane & 15;
  const int fk = lane >> 4;

  // A: 2 thr/row, 32B bf16 each. row=tid>>1, half=tid&1 -> slots 2h,2h+1
  const int ar = tid >> 1, ah = tid & 1;
  int lrA = mt * 128 + ar;
  const unsigned short* asrc = hidden + (size_t)(off + ((lrA < ne) ? lrA : (ne - 1))) * ID + ah * 16;
  const int as0 = (2 * ah) ^ ((ar >> 1) & 3);
  const int as1 = (2 * ah + 1) ^ ((ar >> 1) & 3);

  // B: 2 thr/row, 64B fp32 each. row=tid>>1, half=tid&1
  const float* bsrc = wd + ((size_t)e * HD + nt * 128 + ar) * ID + ah * 16;

  f32x4 acc[4][4] = {};
  u16x8 rA2[4][2];
  f32x4 rB2[4][4];

#define G2_LOAD(kt, p)                                                   \
  do {                                                                   \
    rA2[p][0] = *(const u16x8*)(asrc + (kt) * 32);                       \
    rA2[p][1] = *(const u16x8*)(asrc + (kt) * 32 + 8);                   \
    const float* b_ = bsrc + (kt) * 32;                                  \
    _Pragma("unroll") for (int i = 0; i < 4; ++i)                        \
      rB2[p][i] = *(const f32x4*)(b_ + i * 4);                           \
  } while (0)

#define G2_WRITE(p)                                                      \
  do {                                                                   \
    *(u16x8*)(lds + ((p) & 1) * 8192 + ar * 64 + (as0 << 4)) = rA2[p][0]; \
    *(u16x8*)(lds + ((p) & 1) * 8192 + ar * 64 + (as1 << 4)) = rA2[p][1]; \
    *(bf16x8*)(lds + 16384 + ((p) & 1) * 8192 + ar * 64 + (as0 << 4)) = pack8(rB2[p][0], rB2[p][1]); \
    *(bf16x8*)(lds + 16384 + ((p) & 1) * 8192 + ar * 64 + (as1 << 4)) = pack8(rB2[p][2], rB2[p][3]); \
  } while (0)

#define G2_COMPUTE(p)                                                    \
  do {                                                                   \
    bf16x8 af[4], bb[4];                                                 \
    _Pragma("unroll") for (int mi = 0; mi < 4; ++mi) {                   \
      const int r_ = wrow + mi * 16 + frow;                              \
      af[mi] = *(const bf16x8*)(lds + ((p) & 1) * 8192 + r_ * 64 + SSW(r_, fk)); \
    }                                                                    \
    _Pragma("unroll") for (int ni = 0; ni < 4; ++ni) {                   \
      const int r_ = wcol + ni * 16 + frow;                              \
      bb[ni] = *(const bf16x8*)(lds + 16384 + ((p) & 1) * 8192 + r_ * 64 + SSW(r_, fk)); \
    }                                                                    \
    __builtin_amdgcn_s_setprio(1);                                       \
    _Pragma("unroll") for (int mi = 0; mi < 4; ++mi)                     \
      _Pragma("unroll") for (int ni = 0; ni < 4; ++ni)                   \
        acc[mi][ni] = __builtin_amdgcn_mfma_f32_16x16x32_bf16(af[mi], bb[ni], acc[mi][ni], 0, 0, 0); \
    __builtin_amdgcn_s_setprio(0);                                       \
  } while (0)

  const int NIT = ID / 32;  // 128
  G2_LOAD(0, 0); G2_LOAD(1, 1); G2_LOAD(2, 2); G2_LOAD(3, 3);
  for (int ks = 0; ks < NIT; ks += 4) {
    G2_WRITE(0); bar_lgkm(); if (ks + 4 < NIT) G2_LOAD(ks + 4, 0); G2_COMPUTE(0);
    G2_WRITE(1); bar_lgkm(); if (ks + 5 < NIT) G2_LOAD(ks + 5, 1); G2_COMPUTE(1);
    G2_WRITE(2); bar_lgkm(); if (ks + 6 < NIT) G2_LOAD(ks + 6, 2); G2_COMPUTE(2);
    G2_WRITE(3); bar_lgkm(); if (ks + 7 < NIT) G2_LOAD(ks + 7, 3); G2_COMPUTE(3);
  }
#undef G2_LOAD
#undef G2_WRITE
#undef G2_COMPUTE

#pragma unroll
  for (int mi = 0; mi < 4; ++mi)
#pragma unroll
    for (int j = 0; j < 4; ++j) {
      const int row = wrow + mi * 16 + fk * 4 + j;
      const int grow = mt * 128 + row;
      if (grow < ne) {
        const int t = perm[off + grow];
        float* orow = out + (size_t)t * HD + nt * 128 + wcol;
#pragma unroll
        for (int ni = 0; ni < 4; ++ni) orow[ni * 16 + frow] = acc[mi][ni][j];
      }
    }
}

extern "C" void kernel_launch(void* const* d_in, const int* in_sizes, int n_in,
                              void* d_out, int out_size, void* d_ws, size_t ws_size,
                              hipStream_t stream) {
  const float* x  = (const float*)d_in[0];
  const float* gw = (const float*)d_in[1];
  const float* wg = (const float*)d_in[2];
  const float* wu = (const float*)d_in[3];
  const float* wd = (const float*)d_in[4];
  float* out = (float*)d_out;
  float* logits = out + (size_t)TOK * HD;

  unsigned short* hidden = (unsigned short*)d_ws;                       // 33.55 MB
  unsigned short* xp = (unsigned short*)((char*)d_ws + 33554432);       // 8.39 MB
  int* meta = (int*)((char*)d_ws + 33554432 + 8388608);
  int* counts  = meta;        // [8]
  int* counts2 = meta + 8;    // [8]
  int* offsets = meta + 16;   // [8]
  int* top1    = meta + 24;   // [TOK]
  int* perm    = meta + 24 + TOK;  // [TOK]

  init_k<<<1, 64, 0, stream>>>(meta);
  router_k<<<TOK / 4, 256, 0, stream>>>(x, gw, logits, top1);
  hist_k<<<TOK / 256, 256, 0, stream>>>(top1, counts);
  offsets_k<<<1, 64, 0, stream>>>(counts, offsets);
  scatter_k<<<TOK / 256, 256, 0, stream>>>(top1, offsets, counts2, perm);
  xp_k<<<TOK / 4, 256, 0, stream>>>(x, perm, xp);
  gemm1_k<<<256 * (TOK / 128), 512, 0, stream>>>(xp, wg, wu, counts, offsets, hidden);
  gemm2_k<<<64 * (TOK / 128), 256, 0, stream>>>(hidden, wd, perm, counts, offsets, out);
}

// Round 11
// 368.845 us; speedup vs baseline: 1.2062x; 1.2062x over previous
//
#include <hip/hip_runtime.h>

#define TOK 4096
#define HD 1024
#define ID 4096
#define NE 8
#define MAXT 40   // max m-tiles: sum ceil(ne/128) <= 32 + 8

typedef __attribute__((ext_vector_type(4))) float f32x4;
typedef __attribute__((ext_vector_type(8))) __bf16 bf16x8;
typedef __attribute__((ext_vector_type(8))) unsigned short u16x8;

// LDS rows are 64B (BK=32 bf16) = 4 x 16B slots; swizzle slot s -> s ^ ((row>>1)&3).
#define SSW(r, s) ((((s) ^ (((r) >> 1) & 3))) << 4)

// compiler emits v_cvt_pk_bf16_f32 (RNE) for scalar casts -- do NOT hand-roll (m240)
__device__ __forceinline__ bf16x8 pack8(f32x4 a, f32x4 b) {
  bf16x8 r;
#pragma unroll
  for (int i = 0; i < 4; ++i) { r[i] = (__bf16)a[i]; r[i + 4] = (__bf16)b[i]; }
  return r;
}

__device__ __forceinline__ float gelu_tanh(float g) {
  float z = 0.7978845608028654f * (g + 0.044715f * g * g * g);
  float t = __expf(-2.0f * z);
  return g / (1.0f + t);
}

// barrier that does NOT drain vmcnt: LDS ordering via lgkmcnt(0), global prefetch stays in flight
__device__ __forceinline__ void bar_lgkm() {
  asm volatile("s_waitcnt lgkmcnt(0)" ::: "memory");
  __builtin_amdgcn_s_barrier();
}

__global__ void init_k(int* __restrict__ meta) {
  if (threadIdx.x < 16) meta[threadIdx.x] = 0;
}

// one wave per token: fp32 logits (argmax must match numpy fp32), top1 via first-max
__global__ void router_k(const float* __restrict__ x, const float* __restrict__ gw,
                         float* __restrict__ logits, int* __restrict__ top1) {
  const int wid = threadIdx.x >> 6;
  const int lane = threadIdx.x & 63;
  const int t = blockIdx.x * 4 + wid;
  const float* xr = x + (size_t)t * HD;
  float acc[NE];
#pragma unroll
  for (int e = 0; e < NE; ++e) acc[e] = 0.0f;
#pragma unroll
  for (int c = 0; c < 4; ++c) {
    const int k = (c * 64 + lane) * 4;
    f32x4 xv = *(const f32x4*)(xr + k);
#pragma unroll
    for (int e = 0; e < NE; ++e) {
      f32x4 gv = *(const f32x4*)(gw + e * HD + k);
      acc[e] += xv[0] * gv[0] + xv[1] * gv[1] + xv[2] * gv[2] + xv[3] * gv[3];
    }
  }
#pragma unroll
  for (int off = 32; off > 0; off >>= 1) {
#pragma unroll
    for (int e = 0; e < NE; ++e) acc[e] += __shfl_xor(acc[e], off, 64);
  }
  if (lane == 0) {
    int best = 0; float bv = acc[0];
#pragma unroll
    for (int e = 1; e < NE; ++e) if (acc[e] > bv) { bv = acc[e]; best = e; }
    top1[t] = best;
#pragma unroll
    for (int e = 0; e < NE; ++e) logits[(size_t)t * NE + e] = acc[e];
  }
}

__global__ void hist_k(const int* __restrict__ top1, int* __restrict__ counts) {
  int t = blockIdx.x * 256 + threadIdx.x;
  atomicAdd(&counts[top1[t]], 1);
}

// offsets + compacted tile map: tilemap[t] = (e<<8)|mt for every REAL m-tile
__global__ void offsets_k(const int* __restrict__ counts, int* __restrict__ offsets,
                          int* __restrict__ tilemap, int* __restrict__ ntiles) {
  if (threadIdx.x == 0) {
    int s = 0;
    for (int e = 0; e < NE; ++e) { offsets[e] = s; s += counts[e]; }
    int t = 0;
    for (int e = 0; e < NE; ++e) {
      int nt_e = (counts[e] + 127) >> 7;
      for (int i = 0; i < nt_e; ++i) tilemap[t++] = (e << 8) | i;
    }
    *ntiles = t;
  }
}

__global__ void scatter_k(const int* __restrict__ top1, const int* __restrict__ offsets,
                          int* __restrict__ counts2, int* __restrict__ perm) {
  int t = blockIdx.x * 256 + threadIdx.x;
  int e = top1[t];
  int slot = atomicAdd(&counts2[e], 1);
  perm[offsets[e] + slot] = t;
}

// compact permuted bf16 copy of x: xp[p,:] = bf16(x[perm[p],:])
__global__ void xp_k(const float* __restrict__ x, const int* __restrict__ perm,
                     unsigned short* __restrict__ xp) {
  const int p = blockIdx.x * 4 + (threadIdx.x >> 6);
  const int lane = threadIdx.x & 63;
  const float* src = x + (size_t)perm[p] * HD + lane * 16;
  unsigned short* dst = xp + (size_t)p * HD + lane * 16;
  f32x4 v0 = *(const f32x4*)(src);
  f32x4 v1 = *(const f32x4*)(src + 4);
  f32x4 v2 = *(const f32x4*)(src + 8);
  f32x4 v3 = *(const f32x4*)(src + 12);
  *(bf16x8*)(dst) = pack8(v0, v1);
  *(bf16x8*)(dst + 8) = pack8(v2, v3);
}

// gemm1: tile-compacted grid (t,nt): t -> (e,mt) via tilemap. BM=128 x BN=128, BK=32.
// 512 thr / 8 waves = 2wm x 4wn; each wave owns 64x32 patch with BOTH gate and up acc
// (accg[4][2]+accu[4][2] = 64 AGPR) -> lane-local gelu fusion, NO exchange epilogue.
// LDS 48KB (A dbuf 2x8K, B dbuf 2x16K: rows 0-127 gate, 128-255 up) -> 3 blocks/CU.
__global__ __launch_bounds__(512, 2) void gemm1_k(
    const unsigned short* __restrict__ xp, const float* __restrict__ wg,
    const float* __restrict__ wu, const int* __restrict__ counts,
    const int* __restrict__ offsets, const int* __restrict__ tilemap,
    const int* __restrict__ ntiles, unsigned short* __restrict__ hidden) {
  const int t = blockIdx.x >> 5;
  const int nt = blockIdx.x & 31;
  if (t >= *ntiles) return;
  const int tm = tilemap[t];
  const int e = tm >> 8, mt = tm & 255;
  const int ne = counts[e];
  const int off = offsets[e];

  __shared__ __align__(16) char lds[49152];  // A 2x8K @0, B 2x16K @16384

  const int tid = threadIdx.x;
  const int lane = tid & 63;
  const int wid = tid >> 6;
  const int wm = wid >> 2;            // 0..1 -> rows wm*64
  const int wn = wid & 3;             // 0..3 -> cols wn*32 (gate AND up)
  const int wrow = wm * 64;
  const int frow = lane & 15;
  const int fk = lane >> 4;           // 0..3 slot

  // A staging: 4 thr/row, 16B each. row=tid>>2, slot=tid&3
  const int ar = tid >> 2, as = tid & 3;
  int tokrow = off + mt * 128 + ar;
  if (tokrow >= TOK) tokrow = TOK - 1;           // masked at store
  const unsigned short* asrc = xp + (size_t)tokrow * HD + as * 8;

  // B staging: 2 thr/row, 64B fp32 each. row=tid>>1 (0-127 gate,128-255 up), half=tid&1
  const int br = tid >> 1, bh = tid & 1;
  const float* bsrc = (br < 128)
      ? wg + ((size_t)e * ID + nt * 128 + br) * HD + bh * 16
      : wu + ((size_t)e * ID + nt * 128 + (br - 128)) * HD + bh * 16;
  const int bs0 = (2 * bh) ^ ((br >> 1) & 3);
  const int bs1 = (2 * bh + 1) ^ ((br >> 1) & 3);

  f32x4 accg[4][2] = {};
  f32x4 accu[4][2] = {};
  u16x8 rAv[2];
  f32x4 rBv[2][4];

#define G1_LOAD(kt, p)                                                   \
  do {                                                                   \
    rAv[p] = *(const u16x8*)(asrc + (kt) * 32);                          \
    const float* b_ = bsrc + (kt) * 32;                                  \
    _Pragma("unroll") for (int i = 0; i < 4; ++i)                        \
      rBv[p][i] = *(const f32x4*)(b_ + i * 4);                           \
  } while (0)

#define G1_WRITE(p)                                                      \
  do {                                                                   \
    *(u16x8*)(lds + (p) * 8192 + ar * 64 + SSW(ar, as)) = rAv[p];        \
    *(bf16x8*)(lds + 16384 + (p) * 16384 + br * 64 + (bs0 << 4)) = pack8(rBv[p][0], rBv[p][1]); \
    *(bf16x8*)(lds + 16384 + (p) * 16384 + br * 64 + (bs1 << 4)) = pack8(rBv[p][2], rBv[p][3]); \
  } while (0)

#define G1_COMPUTE(p)                                                    \
  do {                                                                   \
    bf16x8 af[4], bg[2], bu[2];                                          \
    _Pragma("unroll") for (int mi = 0; mi < 4; ++mi) {                   \
      const int r_ = wrow + mi * 16 + frow;                              \
      af[mi] = *(const bf16x8*)(lds + (p) * 8192 + r_ * 64 + SSW(r_, fk)); \
    }                                                                    \
    _Pragma("unroll") for (int ni = 0; ni < 2; ++ni) {                   \
      const int rg_ = wn * 32 + ni * 16 + frow;                          \
      const int ru_ = 128 + wn * 32 + ni * 16 + frow;                    \
      bg[ni] = *(const bf16x8*)(lds + 16384 + (p) * 16384 + rg_ * 64 + SSW(rg_, fk)); \
      bu[ni] = *(const bf16x8*)(lds + 16384 + (p) * 16384 + ru_ * 64 + SSW(ru_, fk)); \
    }                                                                    \
    __builtin_amdgcn_s_setprio(1);                                       \
    _Pragma("unroll") for (int mi = 0; mi < 4; ++mi)                     \
      _Pragma("unroll") for (int ni = 0; ni < 2; ++ni) {                 \
        accg[mi][ni] = __builtin_amdgcn_mfma_f32_16x16x32_bf16(af[mi], bg[ni], accg[mi][ni], 0, 0, 0); \
        accu[mi][ni] = __builtin_amdgcn_mfma_f32_16x16x32_bf16(af[mi], bu[ni], accu[mi][ni], 0, 0, 0); \
      }                                                                  \
    __builtin_amdgcn_s_setprio(0);                                       \
  } while (0)

  const int NIT = HD / 32;  // 32
  G1_LOAD(0, 0);
  G1_LOAD(1, 1);
  for (int ks = 0; ks < NIT; ks += 2) {
    G1_WRITE(0); bar_lgkm(); if (ks + 2 < NIT) G1_LOAD(ks + 2, 0); G1_COMPUTE(0);
    G1_WRITE(1); bar_lgkm(); if (ks + 3 < NIT) G1_LOAD(ks + 3, 1); G1_COMPUTE(1);
  }
#undef G1_LOAD
#undef G1_WRITE
#undef G1_COMPUTE

  // lane-local fusion epilogue
#pragma unroll
  for (int mi = 0; mi < 4; ++mi)
#pragma unroll
    for (int j = 0; j < 4; ++j) {
      const int grow = mt * 128 + wrow + mi * 16 + fk * 4 + j;
      if (grow < ne) {
        unsigned short* hrow = hidden + (size_t)(off + grow) * ID + nt * 128 + wn * 32;
#pragma unroll
        for (int ni = 0; ni < 2; ++ni) {
          __bf16 hb = (__bf16)(gelu_tanh(accg[mi][ni][j]) * accu[mi][ni][j]);
          hrow[ni * 16 + frow] = __builtin_bit_cast(unsigned short, hb);
        }
      }
    }
}

// gemm2: tile-compacted (t,nt). BM=128 x BN=64, BK=32, 256 thr / 4 waves (2wm x 2wn),
// wave 64x32, acc[4][2]=32 AGPR. LDS 24KB (A 2x8K, B 2x4K) -> high blocks/CU.
__global__ __launch_bounds__(256, 2) void gemm2_k(
    const unsigned short* __restrict__ hidden, const float* __restrict__ wd,
    const int* __restrict__ perm, const int* __restrict__ counts,
    const int* __restrict__ offsets, const int* __restrict__ tilemap,
    const int* __restrict__ ntiles, float* __restrict__ out) {
  const int t = blockIdx.x >> 4;
  const int nt = blockIdx.x & 15;
  if (t >= *ntiles) return;
  const int tm = tilemap[t];
  const int e = tm >> 8, mt = tm & 255;
  const int ne = counts[e];
  const int off = offsets[e];

  __shared__ __align__(16) char lds[24576];  // A 2x8K @0, B 2x4K @16384

  const int tid = threadIdx.x;
  const int lane = tid & 63;
  const int wid = tid >> 6;
  const int wm = wid >> 1, wn = wid & 1;
  const int wrow = wm * 64, wcol = wn * 32;
  const int frow = lane & 15;
  const int fk = lane >> 4;

  // A: 2 thr/row, 32B bf16 each. row=tid>>1, half=tid&1 -> slots 2h,2h+1
  const int ar = tid >> 1, ah = tid & 1;
  int lrA = mt * 128 + ar;
  const unsigned short* asrc = hidden + (size_t)(off + ((lrA < ne) ? lrA : (ne - 1))) * ID + ah * 16;
  const int as0 = (2 * ah) ^ ((ar >> 1) & 3);
  const int as1 = (2 * ah + 1) ^ ((ar >> 1) & 3);

  // B: 4 thr/row, 32B fp32 each. row=tid>>2 (0..63), quarter=tid&3 -> slot q
  const int br = tid >> 2, bq = tid & 3;
  const float* bsrc = wd + ((size_t)e * HD + nt * 64 + br) * ID + bq * 8;
  const int bsl = bq ^ ((br >> 1) & 3);

  f32x4 acc[4][2] = {};
  u16x8 rA2[2][2];
  f32x4 rB2[2][2];

#define G2_LOAD(kt, p)                                                   \
  do {                                                                   \
    rA2[p][0] = *(const u16x8*)(asrc + (kt) * 32);                       \
    rA2[p][1] = *(const u16x8*)(asrc + (kt) * 32 + 8);                   \
    const float* b_ = bsrc + (kt) * 32;                                  \
    rB2[p][0] = *(const f32x4*)b_;                                       \
    rB2[p][1] = *(const f32x4*)(b_ + 4);                                 \
  } while (0)

#define G2_WRITE(p)                                                      \
  do {                                                                   \
    *(u16x8*)(lds + (p) * 8192 + ar * 64 + (as0 << 4)) = rA2[p][0];      \
    *(u16x8*)(lds + (p) * 8192 + ar * 64 + (as1 << 4)) = rA2[p][1];      \
    *(bf16x8*)(lds + 16384 + (p) * 4096 + br * 64 + (bsl << 4)) = pack8(rB2[p][0], rB2[p][1]); \
  } while (0)

#define G2_COMPUTE(p)                                                    \
  do {                                                                   \
    bf16x8 af[4], bb[2];                                                 \
    _Pragma("unroll") for (int mi = 0; mi < 4; ++mi) {                   \
      const int r_ = wrow + mi * 16 + frow;                              \
      af[mi] = *(const bf16x8*)(lds + (p) * 8192 + r_ * 64 + SSW(r_, fk)); \
    }                                                                    \
    _Pragma("unroll") for (int ni = 0; ni < 2; ++ni) {                   \
      const int r_ = wcol + ni * 16 + frow;                              \
      bb[ni] = *(const bf16x8*)(lds + 16384 + (p) * 4096 + r_ * 64 + SSW(r_, fk)); \
    }                                                                    \
    __builtin_amdgcn_s_setprio(1);                                       \
    _Pragma("unroll") for (int mi = 0; mi < 4; ++mi)                     \
      _Pragma("unroll") for (int ni = 0; ni < 2; ++ni)                   \
        acc[mi][ni] = __builtin_amdgcn_mfma_f32_16x16x32_bf16(af[mi], bb[ni], acc[mi][ni], 0, 0, 0); \
    __builtin_amdgcn_s_setprio(0);                                       \
  } while (0)

  const int NIT = ID / 32;  // 128
  G2_LOAD(0, 0);
  G2_LOAD(1, 1);
  for (int ks = 0; ks < NIT; ks += 2) {
    G2_WRITE(0); bar_lgkm(); if (ks + 2 < NIT) G2_LOAD(ks + 2, 0); G2_COMPUTE(0);
    G2_WRITE(1); bar_lgkm(); if (ks + 3 < NIT) G2_LOAD(ks + 3, 1); G2_COMPUTE(1);
  }
#undef G2_LOAD
#undef G2_WRITE
#undef G2_COMPUTE

#pragma unroll
  for (int mi = 0; mi < 4; ++mi)
#pragma unroll
    for (int j = 0; j < 4; ++j) {
      const int row = wrow + mi * 16 + fk * 4 + j;
      const int grow = mt * 128 + row;
      if (grow < ne) {
        const int tk = perm[off + grow];
        float* orow = out + (size_t)tk * HD + nt * 64 + wcol;
#pragma unroll
        for (int ni = 0; ni < 2; ++ni) orow[ni * 16 + frow] = acc[mi][ni][j];
      }
    }
}

extern "C" void kernel_launch(void* const* d_in, const int* in_sizes, int n_in,
                              void* d_out, int out_size, void* d_ws, size_t ws_size,
                              hipStream_t stream) {
  const float* x  = (const float*)d_in[0];
  const float* gw = (const float*)d_in[1];
  const float* wg = (const float*)d_in[2];
  const float* wu = (const float*)d_in[3];
  const float* wd = (const float*)d_in[4];
  float* out = (float*)d_out;
  float* logits = out + (size_t)TOK * HD;

  unsigned short* hidden = (unsigned short*)d_ws;                       // 33.55 MB
  unsigned short* xp = (unsigned short*)((char*)d_ws + 33554432);       // 8.39 MB
  int* meta = (int*)((char*)d_ws + 33554432 + 8388608);
  int* counts  = meta;             // [8]
  int* counts2 = meta + 8;         // [8]
  int* offsets = meta + 16;        // [8]
  int* tilemap = meta + 24;        // [MAXT]
  int* ntiles  = meta + 24 + MAXT; // [1]
  int* top1    = meta + 72;        // [TOK]
  int* perm    = meta + 72 + TOK;  // [TOK]

  init_k<<<1, 64, 0, stream>>>(meta);
  router_k<<<TOK / 4, 256, 0, stream>>>(x, gw, logits, top1);
  hist_k<<<TOK / 256, 256, 0, stream>>>(top1, counts);
  offsets_k<<<1, 64, 0, stream>>>(counts, offsets, tilemap, ntiles);
  scatter_k<<<TOK / 256, 256, 0, stream>>>(top1, offsets, counts2, perm);
  xp_k<<<TOK / 4, 256, 0, stream>>>(x, perm, xp);
  gemm1_k<<<MAXT * 32, 512, 0, stream>>>(xp, wg, wu, counts, offsets, tilemap, ntiles, hidden);
  gemm2_k<<<MAXT * 16, 256, 0, stream>>>(hidden, wd, perm, counts, offsets, tilemap, ntiles, out);
}

// Round 12
// 322.219 us; speedup vs baseline: 1.3807x; 1.1447x over previous
//
#include <hip/hip_runtime.h>

#define TOK 4096
#define HD 1024
#define ID 4096
#define NE 8
#define MAXT 40   // max m-tiles: sum ceil(ne/128) <= 32 + 8

typedef __attribute__((ext_vector_type(4))) float f32x4;
typedef __attribute__((ext_vector_type(8))) __bf16 bf16x8;
typedef __attribute__((ext_vector_type(8))) unsigned short u16x8;

// LDS rows are 64B (BK=32 bf16) = 4 x 16B slots; swizzle slot s -> s ^ ((row>>1)&3).
#define SSW(r, s) ((((s) ^ (((r) >> 1) & 3))) << 4)

// compiler emits v_cvt_pk_bf16_f32 (RNE) for scalar casts -- do NOT hand-roll (m240)
__device__ __forceinline__ bf16x8 pack8(f32x4 a, f32x4 b) {
  bf16x8 r;
#pragma unroll
  for (int i = 0; i < 4; ++i) { r[i] = (__bf16)a[i]; r[i + 4] = (__bf16)b[i]; }
  return r;
}

__device__ __forceinline__ float gelu_tanh(float g) {
  float z = 0.7978845608028654f * (g + 0.044715f * g * g * g);
  float t = __expf(-2.0f * z);
  return g / (1.0f + t);
}

// barrier that does NOT drain vmcnt: LDS ordering via lgkmcnt(0), global prefetch stays in flight
__device__ __forceinline__ void bar_lgkm() {
  asm volatile("s_waitcnt lgkmcnt(0)" ::: "memory");
  __builtin_amdgcn_s_barrier();
}

__global__ void init_k(int* __restrict__ meta) {
  if (threadIdx.x < 16) meta[threadIdx.x] = 0;
}

// one wave per token: fp32 logits (argmax must match numpy fp32), top1 via first-max
__global__ void router_k(const float* __restrict__ x, const float* __restrict__ gw,
                         float* __restrict__ logits, int* __restrict__ top1) {
  const int wid = threadIdx.x >> 6;
  const int lane = threadIdx.x & 63;
  const int t = blockIdx.x * 4 + wid;
  const float* xr = x + (size_t)t * HD;
  float acc[NE];
#pragma unroll
  for (int e = 0; e < NE; ++e) acc[e] = 0.0f;
#pragma unroll
  for (int c = 0; c < 4; ++c) {
    const int k = (c * 64 + lane) * 4;
    f32x4 xv = *(const f32x4*)(xr + k);
#pragma unroll
    for (int e = 0; e < NE; ++e) {
      f32x4 gv = *(const f32x4*)(gw + e * HD + k);
      acc[e] += xv[0] * gv[0] + xv[1] * gv[1] + xv[2] * gv[2] + xv[3] * gv[3];
    }
  }
#pragma unroll
  for (int off = 32; off > 0; off >>= 1) {
#pragma unroll
    for (int e = 0; e < NE; ++e) acc[e] += __shfl_xor(acc[e], off, 64);
  }
  if (lane == 0) {
    int best = 0; float bv = acc[0];
#pragma unroll
    for (int e = 1; e < NE; ++e) if (acc[e] > bv) { bv = acc[e]; best = e; }
    top1[t] = best;
#pragma unroll
    for (int e = 0; e < NE; ++e) logits[(size_t)t * NE + e] = acc[e];
  }
}

__global__ void hist_k(const int* __restrict__ top1, int* __restrict__ counts) {
  int t = blockIdx.x * 256 + threadIdx.x;
  atomicAdd(&counts[top1[t]], 1);
}

// offsets + compacted tile map: tilemap[t] = (e<<8)|mt for every REAL m-tile
__global__ void offsets_k(const int* __restrict__ counts, int* __restrict__ offsets,
                          int* __restrict__ tilemap, int* __restrict__ ntiles) {
  if (threadIdx.x == 0) {
    int s = 0;
    for (int e = 0; e < NE; ++e) { offsets[e] = s; s += counts[e]; }
    int t = 0;
    for (int e = 0; e < NE; ++e) {
      int nt_e = (counts[e] + 127) >> 7;
      for (int i = 0; i < nt_e; ++i) tilemap[t++] = (e << 8) | i;
    }
    *ntiles = t;
  }
}

__global__ void scatter_k(const int* __restrict__ top1, const int* __restrict__ offsets,
                          int* __restrict__ counts2, int* __restrict__ perm) {
  int t = blockIdx.x * 256 + threadIdx.x;
  int e = top1[t];
  int slot = atomicAdd(&counts2[e], 1);
  perm[offsets[e] + slot] = t;
}

// compact permuted bf16 copy of x: xp[p,:] = bf16(x[perm[p],:])
__global__ void xp_k(const float* __restrict__ x, const int* __restrict__ perm,
                     unsigned short* __restrict__ xp) {
  const int p = blockIdx.x * 4 + (threadIdx.x >> 6);
  const int lane = threadIdx.x & 63;
  const float* src = x + (size_t)perm[p] * HD + lane * 16;
  unsigned short* dst = xp + (size_t)p * HD + lane * 16;
  f32x4 v0 = *(const f32x4*)(src);
  f32x4 v1 = *(const f32x4*)(src + 4);
  f32x4 v2 = *(const f32x4*)(src + 8);
  f32x4 v3 = *(const f32x4*)(src + 12);
  *(bf16x8*)(dst) = pack8(v0, v1);
  *(bf16x8*)(dst + 8) = pack8(v2, v3);
}

// gemm1: BM=128 tok x BN=64 out-cols, BK=32. 512 thr / 8 waves = 2wm x {2 gate, 2 up},
// wave 64x32 SINGLE-ROLE: acc[4][2] = 32 AGPR -> total regs <= 128 -> 4 waves/SIMD
// -> 2 co-resident blocks/CU (the R11 occupancy fix). B-LDS = 128 rows (64 gate + 64 up).
// dbuf LDS + depth-2 reg prefetch, one lgkm-barrier per tile. Gate/up fused via
// LDS exchange epilogue (reuses dead tile space).
__global__ __launch_bounds__(512, 4) void gemm1_k(
    const unsigned short* __restrict__ xp, const float* __restrict__ wg,
    const float* __restrict__ wu, const int* __restrict__ counts,
    const int* __restrict__ offsets, const int* __restrict__ tilemap,
    const int* __restrict__ ntiles, unsigned short* __restrict__ hidden) {
  const int t = blockIdx.x >> 6;
  const int nt = blockIdx.x & 63;          // 64 nt tiles of 64 cols
  if (t >= *ntiles) return;
  const int tm = tilemap[t];
  const int e = tm >> 8, mt = tm & 255;
  const int ne = counts[e];
  const int off = offsets[e];

  __shared__ __align__(16) char lds[36864];  // A 2x8K @0, B 2x8K @16384; epilogue ex [128][68] f32

  const int tid = threadIdx.x;
  const int lane = tid & 63;
  const int wid = tid >> 6;
  const int wm = wid >> 2;                 // 0..1 -> rows wm*64
  const int role = (wid >> 1) & 1;         // 0 = gate, 1 = up
  const int wc = (wid & 1) * 32;           // col chunk within 64
  const int wrow = wm * 64;
  const int brow0 = role * 64 + wc;        // B frag row base
  const int frow = lane & 15;
  const int fk = lane >> 4;                // 0..3 slot

  // A staging: 4 thr/row, 16B each. row=tid>>2, slot=tid&3
  const int ar = tid >> 2, as = tid & 3;
  int tokrow = off + mt * 128 + ar;
  if (tokrow >= TOK) tokrow = TOK - 1;     // masked at store
  const unsigned short* asrc = xp + (size_t)tokrow * HD + as * 8;

  // B staging: 4 thr/row, 32B fp32 each. rows 0-63 gate, 64-127 up
  const int br = tid >> 2, bq = tid & 3;
  const float* bsrc = (br < 64)
      ? wg + ((size_t)e * ID + nt * 64 + br) * HD + bq * 8
      : wu + ((size_t)e * ID + nt * 64 + (br - 64)) * HD + bq * 8;
  const int bsl = bq ^ ((br >> 1) & 3);

  f32x4 acc[4][2] = {};
  u16x8 rAv[2];
  f32x4 rBv[2][2];

#define G1_LOAD(kt, p)                                                   \
  do {                                                                   \
    rAv[p] = *(const u16x8*)(asrc + (kt) * 32);                          \
    const float* b_ = bsrc + (kt) * 32;                                  \
    rBv[p][0] = *(const f32x4*)b_;                                       \
    rBv[p][1] = *(const f32x4*)(b_ + 4);                                 \
  } while (0)

#define G1_WRITE(p)                                                      \
  do {                                                                   \
    *(u16x8*)(lds + (p) * 8192 + ar * 64 + SSW(ar, as)) = rAv[p];        \
    *(bf16x8*)(lds + 16384 + (p) * 8192 + br * 64 + (bsl << 4)) = pack8(rBv[p][0], rBv[p][1]); \
  } while (0)

#define G1_COMPUTE(p)                                                    \
  do {                                                                   \
    bf16x8 af[4], bf_[2];                                                \
    _Pragma("unroll") for (int mi = 0; mi < 4; ++mi) {                   \
      const int r_ = wrow + mi * 16 + frow;                              \
      af[mi] = *(const bf16x8*)(lds + (p) * 8192 + r_ * 64 + SSW(r_, fk)); \
    }                                                                    \
    _Pragma("unroll") for (int ni = 0; ni < 2; ++ni) {                   \
      const int r_ = brow0 + ni * 16 + frow;                             \
      bf_[ni] = *(const bf16x8*)(lds + 16384 + (p) * 8192 + r_ * 64 + SSW(r_, fk)); \
    }                                                                    \
    __builtin_amdgcn_s_setprio(1);                                       \
    _Pragma("unroll") for (int mi = 0; mi < 4; ++mi)                     \
      _Pragma("unroll") for (int ni = 0; ni < 2; ++ni)                   \
        acc[mi][ni] = __builtin_amdgcn_mfma_f32_16x16x32_bf16(af[mi], bf_[ni], acc[mi][ni], 0, 0, 0); \
    __builtin_amdgcn_s_setprio(0);                                       \
  } while (0)

  const int NIT = HD / 32;  // 32
  G1_LOAD(0, 0);
  G1_LOAD(1, 1);
  for (int ks = 0; ks < NIT; ks += 2) {
    G1_WRITE(0); bar_lgkm(); if (ks + 2 < NIT) G1_LOAD(ks + 2, 0); G1_COMPUTE(0);
    G1_WRITE(1); bar_lgkm(); if (ks + 3 < NIT) G1_LOAD(ks + 3, 1); G1_COMPUTE(1);
  }
#undef G1_LOAD
#undef G1_WRITE
#undef G1_COMPUTE

  // epilogue: gate waves -> LDS exchange [128][68] f32; up waves fuse gelu(g)*u -> hidden bf16
  __syncthreads();
  float* ex = (float*)lds;
  if (role == 0) {
#pragma unroll
    for (int mi = 0; mi < 4; ++mi)
#pragma unroll
      for (int ni = 0; ni < 2; ++ni)
#pragma unroll
        for (int j = 0; j < 4; ++j) {
          const int row = wrow + mi * 16 + fk * 4 + j;
          ex[row * 68 + wc + ni * 16 + frow] = acc[mi][ni][j];
        }
  }
  __syncthreads();
  if (role == 1) {
#pragma unroll
    for (int mi = 0; mi < 4; ++mi)
#pragma unroll
      for (int j = 0; j < 4; ++j) {
        const int row = wrow + mi * 16 + fk * 4 + j;
        const int grow = mt * 128 + row;
        if (grow < ne) {
          unsigned short* hrow = hidden + (size_t)(off + grow) * ID + nt * 64;
#pragma unroll
          for (int ni = 0; ni < 2; ++ni) {
            const int col = wc + ni * 16 + frow;
            float g = ex[row * 68 + col];
            __bf16 hb = (__bf16)(gelu_tanh(g) * acc[mi][ni][j]);
            hrow[col] = __builtin_bit_cast(unsigned short, hb);
          }
        }
      }
  }
}

// gemm2: tile-compacted (t,nt). BM=128 x BN=64, BK=32, 256 thr / 4 waves (2wm x 2wn),
// wave 64x32, acc[4][2]=32 AGPR, launch_bounds(256,4) -> 4 waves/SIMD -> 4 blocks/CU.
__global__ __launch_bounds__(256, 4) void gemm2_k(
    const unsigned short* __restrict__ hidden, const float* __restrict__ wd,
    const int* __restrict__ perm, const int* __restrict__ counts,
    const int* __restrict__ offsets, const int* __restrict__ tilemap,
    const int* __restrict__ ntiles, float* __restrict__ out) {
  const int t = blockIdx.x >> 4;
  const int nt = blockIdx.x & 15;
  if (t >= *ntiles) return;
  const int tm = tilemap[t];
  const int e = tm >> 8, mt = tm & 255;
  const int ne = counts[e];
  const int off = offsets[e];

  __shared__ __align__(16) char lds[24576];  // A 2x8K @0, B 2x4K @16384

  const int tid = threadIdx.x;
  const int lane = tid & 63;
  const int wid = tid >> 6;
  const int wm = wid >> 1, wn = wid & 1;
  const int wrow = wm * 64, wcol = wn * 32;
  const int frow = lane & 15;
  const int fk = lane >> 4;

  // A: 2 thr/row, 32B bf16 each. row=tid>>1, half=tid&1 -> slots 2h,2h+1
  const int ar = tid >> 1, ah = tid & 1;
  int lrA = mt * 128 + ar;
  const unsigned short* asrc = hidden + (size_t)(off + ((lrA < ne) ? lrA : (ne - 1))) * ID + ah * 16;
  const int as0 = (2 * ah) ^ ((ar >> 1) & 3);
  const int as1 = (2 * ah + 1) ^ ((ar >> 1) & 3);

  // B: 4 thr/row, 32B fp32 each. row=tid>>2 (0..63), quarter=tid&3 -> slot q
  const int br = tid >> 2, bq = tid & 3;
  const float* bsrc = wd + ((size_t)e * HD + nt * 64 + br) * ID + bq * 8;
  const int bsl = bq ^ ((br >> 1) & 3);

  f32x4 acc[4][2] = {};
  u16x8 rA2[2][2];
  f32x4 rB2[2][2];

#define G2_LOAD(kt, p)                                                   \
  do {                                                                   \
    rA2[p][0] = *(const u16x8*)(asrc + (kt) * 32);                       \
    rA2[p][1] = *(const u16x8*)(asrc + (kt) * 32 + 8);                   \
    const float* b_ = bsrc + (kt) * 32;                                  \
    rB2[p][0] = *(const f32x4*)b_;                                       \
    rB2[p][1] = *(const f32x4*)(b_ + 4);                                 \
  } while (0)

#define G2_WRITE(p)                                                      \
  do {                                                                   \
    *(u16x8*)(lds + (p) * 8192 + ar * 64 + (as0 << 4)) = rA2[p][0];      \
    *(u16x8*)(lds + (p) * 8192 + ar * 64 + (as1 << 4)) = rA2[p][1];      \
    *(bf16x8*)(lds + 16384 + (p) * 4096 + br * 64 + (bsl << 4)) = pack8(rB2[p][0], rB2[p][1]); \
  } while (0)

#define G2_COMPUTE(p)                                                    \
  do {                                                                   \
    bf16x8 af[4], bb[2];                                                 \
    _Pragma("unroll") for (int mi = 0; mi < 4; ++mi) {                   \
      const int r_ = wrow + mi * 16 + frow;                              \
      af[mi] = *(const bf16x8*)(lds + (p) * 8192 + r_ * 64 + SSW(r_, fk)); \
    }                                                                    \
    _Pragma("unroll") for (int ni = 0; ni < 2; ++ni) {                   \
      const int r_ = wcol + ni * 16 + frow;                              \
      bb[ni] = *(const bf16x8*)(lds + 16384 + (p) * 4096 + r_ * 64 + SSW(r_, fk)); \
    }                                                                    \
    __builtin_amdgcn_s_setprio(1);                                       \
    _Pragma("unroll") for (int mi = 0; mi < 4; ++mi)                     \
      _Pragma("unroll") for (int ni = 0; ni < 2; ++ni)                   \
        acc[mi][ni] = __builtin_amdgcn_mfma_f32_16x16x32_bf16(af[mi], bb[ni], acc[mi][ni], 0, 0, 0); \
    __builtin_amdgcn_s_setprio(0);                                       \
  } while (0)

  const int NIT = ID / 32;  // 128
  G2_LOAD(0, 0);
  G2_LOAD(1, 1);
  for (int ks = 0; ks < NIT; ks += 2) {
    G2_WRITE(0); bar_lgkm(); if (ks + 2 < NIT) G2_LOAD(ks + 2, 0); G2_COMPUTE(0);
    G2_WRITE(1); bar_lgkm(); if (ks + 3 < NIT) G2_LOAD(ks + 3, 1); G2_COMPUTE(1);
  }
#undef G2_LOAD
#undef G2_WRITE
#undef G2_COMPUTE

#pragma unroll
  for (int mi = 0; mi < 4; ++mi)
#pragma unroll
    for (int j = 0; j < 4; ++j) {
      const int row = wrow + mi * 16 + fk * 4 + j;
      const int grow = mt * 128 + row;
      if (grow < ne) {
        const int tk = perm[off + grow];
        float* orow = out + (size_t)tk * HD + nt * 64 + wcol;
#pragma unroll
        for (int ni = 0; ni < 2; ++ni) orow[ni * 16 + frow] = acc[mi][ni][j];
      }
    }
}

extern "C" void kernel_launch(void* const* d_in, const int* in_sizes, int n_in,
                              void* d_out, int out_size, void* d_ws, size_t ws_size,
                              hipStream_t stream) {
  const float* x  = (const float*)d_in[0];
  const float* gw = (const float*)d_in[1];
  const float* wg = (const float*)d_in[2];
  const float* wu = (const float*)d_in[3];
  const float* wd = (const float*)d_in[4];
  float* out = (float*)d_out;
  float* logits = out + (size_t)TOK * HD;

  unsigned short* hidden = (unsigned short*)d_ws;                       // 33.55 MB
  unsigned short* xp = (unsigned short*)((char*)d_ws + 33554432);       // 8.39 MB
  int* meta = (int*)((char*)d_ws + 33554432 + 8388608);
  int* counts  = meta;             // [8]
  int* counts2 = meta + 8;         // [8]
  int* offsets = meta + 16;        // [8]
  int* tilemap = meta + 24;        // [MAXT]
  int* ntiles  = meta + 24 + MAXT; // [1]
  int* top1    = meta + 72;        // [TOK]
  int* perm    = meta + 72 + TOK;  // [TOK]

  init_k<<<1, 64, 0, stream>>>(meta);
  router_k<<<TOK / 4, 256, 0, stream>>>(x, gw, logits, top1);
  hist_k<<<TOK / 256, 256, 0, stream>>>(top1, counts);
  offsets_k<<<1, 64, 0, stream>>>(counts, offsets, tilemap, ntiles);
  scatter_k<<<TOK / 256, 256, 0, stream>>>(top1, offsets, counts2, perm);
  xp_k<<<TOK / 4, 256, 0, stream>>>(x, perm, xp);
  gemm1_k<<<MAXT * 64, 512, 0, stream>>>(xp, wg, wu, counts, offsets, tilemap, ntiles, hidden);
  gemm2_k<<<MAXT * 16, 256, 0, stream>>>(hidden, wd, perm, counts, offsets, tilemap, ntiles, out);
}